// Round 1
// baseline (6296.029 us; speedup 1.0000x reference)
//
#include <hip/hip_runtime.h>
#include <hip/hip_bf16.h>
#include <stdint.h>

// Problem constants
constexpr int kT = 512;
constexpr int kBn = 64;
constexpr int kI = 256;
constexpr int kH = 512;

// d_ws byte offsets: bf16 packed weights, K-major [kb][row][8] so lane-consecutive
// rows give coalesced 16B loads.
constexpr uint32_t WHP_OFF  = 0u;        // [64][512][8] bf16 : Wh[h][kb*8+e]
constexpr uint32_t WRSP_OFF = 524288u;   // [32][512][8] bf16 : Wr[h][jb*8+e]+Wr[512+h][jb*8+e]
constexpr uint32_t WSP_OFF  = 786432u;   // [64][128][8] bf16 : Ws[o][kb*8+e]
constexpr uint32_t WEP_OFF  = 917504u;   // [32][512][8] bf16 : We[h][kb*8+e]
constexpr uint32_t BIAS_OFF = 1179648u;  // [512] f32 : be+bh+br[h]+br[512+h]

// d_out element offsets (fp32): output[512][64][512], hid_last[1][64][512], stack_res[64][2][32][64]
constexpr uint32_t OUT_HL = 16777216u;
constexpr uint32_t OUT_SR = 16809984u;

static __device__ __forceinline__ float bitsf(uint32_t u) {
  union { uint32_t u; float f; } c; c.u = u; return c.f;
}

// 8-term bf16-weight x fp32-vector dot; p must be 16B-aligned (LDS)
static __device__ __forceinline__ float dot8(uint4 v, const float* p) {
  float4 a = *(const float4*)p;
  float4 c = *(const float4*)(p + 4);
  float s;
  s  = bitsf(v.x << 16)         * a.x;
  s += bitsf(v.x & 0xffff0000u) * a.y;
  s += bitsf(v.y << 16)         * a.z;
  s += bitsf(v.y & 0xffff0000u) * a.w;
  s += bitsf(v.z << 16)         * c.x;
  s += bitsf(v.z & 0xffff0000u) * c.y;
  s += bitsf(v.w << 16)         * c.z;
  s += bitsf(v.w & 0xffff0000u) * c.w;
  return s;
}

// ---------------- kernel 0: pack weights to bf16 K-major + fold biases ----------------
__global__ __launch_bounds__(256) void pack_kernel(
    const float* __restrict__ Wh, const float* __restrict__ Wr,
    const float* __restrict__ Ws, const float* __restrict__ We,
    const float* __restrict__ be, const float* __restrict__ bh,
    const float* __restrict__ br, char* __restrict__ ws)
{
  uint32_t g = blockIdx.x * 256u + threadIdx.x;
  __hip_bfloat16* whp  = (__hip_bfloat16*)(ws + WHP_OFF);
  __hip_bfloat16* wrsp = (__hip_bfloat16*)(ws + WRSP_OFF);
  __hip_bfloat16* wsp  = (__hip_bfloat16*)(ws + WSP_OFF);
  __hip_bfloat16* wep  = (__hip_bfloat16*)(ws + WEP_OFF);
  float* bias = (float*)(ws + BIAS_OFF);

  if (g < 262144u) {  // WhP: idx = (kb*512+h)*8+e
    uint32_t e = g & 7u, h = (g >> 3) & 511u, kb = g >> 12;
    whp[g] = __float2bfloat16(Wh[h * 512u + kb * 8u + e]);
  }
  if (g < 131072u) {  // WrsP: sum the two stack blocks of Wr
    uint32_t e = g & 7u, h = (g >> 3) & 511u, jb = g >> 12;
    wrsp[g] = __float2bfloat16(Wr[h * 256u + jb * 8u + e] +
                               Wr[(512u + h) * 256u + jb * 8u + e]);
  }
  if (g < 65536u) {   // WsP: idx = (kb*128+o)*8+e
    uint32_t e = g & 7u, o = (g >> 3) & 127u, kb = g >> 10;
    wsp[g] = __float2bfloat16(Ws[o * 512u + kb * 8u + e]);
  }
  if (g < 131072u) {  // WeP: idx = (kb*512+h)*8+e, kb<32
    uint32_t e = g & 7u, h = (g >> 3) & 511u, kb = g >> 12;
    wep[g] = __float2bfloat16(We[h * 256u + kb * 8u + e]);
  }
  if (g < 512u) bias[g] = be[g] + bh[g] + br[g] + br[512u + g];
}

// ---------------- kernel 1: E[t,b,:] = emb @ We.T + all biases -> d_out output region --------
__global__ __launch_bounds__(256) void embed_kernel(
    const float* __restrict__ embs, const char* __restrict__ ws,
    float* __restrict__ out)
{
  __shared__ __align__(16) float embL[16 * 256];
  const uint32_t tid = threadIdx.x;
  const uint32_t r0 = blockIdx.x * 16u;  // 16 rows of the flattened [T*B] dim
  #pragma unroll
  for (int i = 0; i < 16; i++) embL[tid + i * 256] = embs[r0 * 256u + tid + i * 256u];
  __syncthreads();

  const uint4* wep = (const uint4*)(ws + WEP_OFF);
  const float* bias = (const float*)(ws + BIAS_OFF);

  for (int hb = 0; hb < 2; hb++) {
    uint32_t h = hb * 256u + tid;
    float acc[16];
    #pragma unroll
    for (int r = 0; r < 16; r++) acc[r] = 0.f;
    for (int kb = 0; kb < 32; kb++) {
      uint4 v = wep[kb * 512u + h];
      float w0 = bitsf(v.x << 16), w1 = bitsf(v.x & 0xffff0000u);
      float w2 = bitsf(v.y << 16), w3 = bitsf(v.y & 0xffff0000u);
      float w4 = bitsf(v.z << 16), w5 = bitsf(v.z & 0xffff0000u);
      float w6 = bitsf(v.w << 16), w7 = bitsf(v.w & 0xffff0000u);
      #pragma unroll
      for (int r = 0; r < 16; r++) {
        const float4* e4 = (const float4*)&embL[r * 256 + kb * 8];
        float4 a = e4[0], c = e4[1];
        acc[r] += w0 * a.x + w1 * a.y + w2 * a.z + w3 * a.w
                + w4 * c.x + w5 * c.y + w6 * c.z + w7 * c.w;
      }
    }
    float bi = bias[h];
    #pragma unroll
    for (int r = 0; r < 16; r++) out[(r0 + r) * 512u + h] = acc[r] + bi;
  }
}

// ---------------- kernel 2: the recurrence, one WG per batch element, no grid sync ----------
__global__ __launch_bounds__(1024) void rnn_kernel(
    const int* __restrict__ lens, const float* __restrict__ Wa,
    const float* __restrict__ ba, const float* __restrict__ bs,
    const float* __restrict__ memb, const char* __restrict__ ws,
    float* __restrict__ out)
{
  __shared__ __align__(16) float hid[2][512];      // double-buffered hidden
  __shared__ __align__(16) float stk[2][4096];     // double-buffered stack [n][s][d]
  __shared__ __align__(16) float tops[256];        // snapshot of stack[:, :2, :]
  __shared__ __align__(16) float pv[128];          // push_vals
  __shared__ __align__(16) float psPart[8][128];   // push_pre partials
  __shared__ __align__(16) float mhPart[1024];     // mhid partials
  __shared__ float lgts[8];
  __shared__ float pp[2][4];                       // softmax probs per stack
  __shared__ __align__(16) float membL[128];

  const uint32_t tid = threadIdx.x;
  const uint32_t b = blockIdx.x;
  const int len = lens[b];

  const uint4* whp  = (const uint4*)(ws + WHP_OFF);
  const uint4* wrsp = (const uint4*)(ws + WRSP_OFF);
  const uint4* wsp  = (const uint4*)(ws + WSP_OFF);

  // init state
  if (tid < 128) membL[tid] = memb[tid];
  if (tid < 512) hid[0][tid] = 0.f;
  __syncthreads();
  {
    uint32_t c = tid * 4u;
    uint32_t n = c >> 11, d = c & 63u;
    float4 m4 = *(const float4*)&membL[n * 64u + d];
    *(float4*)&stk[0][c] = m4;
  }
  __syncthreads();

  for (int t = 0; t < kT; t++) {
    const int cur = t & 1, nxt = cur ^ 1;
    const float* hc = hid[cur];

    // ---- P1: tops snapshot + push_pre partials + action logits (reads old state)
    if (tid < 256) {
      uint32_t n = tid >> 7, s = (tid >> 6) & 1u, d = tid & 63u;
      tops[tid] = stk[cur][n * 2048u + s * 64u + d];
    }
    {
      uint32_t sub = tid >> 7, o = tid & 127u;
      float acc = 0.f;
      #pragma unroll
      for (int i = 0; i < 8; i++) {
        uint32_t kb = sub + (uint32_t)i * 8u;
        acc += dot8(wsp[kb * 128u + o], &hc[kb * 8u]);
      }
      psPart[sub][o] = acc;
    }
    if (tid < 384) {  // 6 waves, one per action logit
      uint32_t o = tid >> 6, l = tid & 63u;
      float acc = 0.f;
      #pragma unroll
      for (int i = 0; i < 8; i++) acc += Wa[o * 512u + l + i * 64u] * hc[l + i * 64u];
      #pragma unroll
      for (int off = 32; off; off >>= 1) acc += __shfl_down(acc, off, 64);
      if (l == 0) lgts[o] = acc + ba[o];
    }
    __syncthreads();

    // ---- P2: softmax + tanh(push) + mhid partials (reads old hid + tops snapshot)
    if (tid < 2) {
      float l0 = lgts[tid * 3], l1 = lgts[tid * 3 + 1], l2 = lgts[tid * 3 + 2];
      float m = fmaxf(l0, fmaxf(l1, l2));
      float e0 = expf(l0 - m), e1 = expf(l1 - m), e2 = expf(l2 - m);
      float inv = 1.f / (e0 + e1 + e2);
      pp[tid][0] = e0 * inv; pp[tid][1] = e1 * inv; pp[tid][2] = e2 * inv;
    }
    if (tid < 128) {
      float s = bs[tid];
      #pragma unroll
      for (int k = 0; k < 8; k++) s += psPart[k][tid];
      pv[tid] = tanhf(s);
    }
    {
      uint32_t h = tid & 511u, half = tid >> 9;
      // E already contains be+bh+br-sum
      float acc = half ? 0.f : out[((uint32_t)t * 64u + b) * 512u + h];
      uint32_t kb0 = half * 32u;
      #pragma unroll 8
      for (int i = 0; i < 32; i++) {
        uint32_t kb = kb0 + (uint32_t)i;
        acc += dot8(whp[kb * 512u + h], &hc[kb * 8u]);
      }
      uint32_t jb0 = half * 16u;
      #pragma unroll 8
      for (int i = 0; i < 16; i++) {
        uint32_t jb = jb0 + (uint32_t)i;
        acc += dot8(wrsp[jb * 512u + h], &tops[jb * 8u]);
      }
      mhPart[tid] = acc;
    }
    __syncthreads();

    // ---- P3: finalize hid, write output, stack blend (writes new state)
    const bool last = (t == len - 1);
    if (tid < 512) {
      float v = tanhf(mhPart[tid] + mhPart[tid + 512]);
      hid[nxt][tid] = v;
      out[((uint32_t)t * 64u + b) * 512u + tid] = v;
      if (last) out[OUT_HL + b * 512u + tid] = v;
    }
    {
      uint32_t c = tid * 4u;
      uint32_t n = c >> 11, s = (c >> 6) & 31u, d = c & 63u;
      float p0 = pp[n][0], p1 = pp[n][1], p2 = pp[n][2];
      float4 scur = *(const float4*)&stk[cur][c];
      float4 sp = (s == 0) ? *(const float4*)&pv[n * 64u + d]
                           : *(const float4*)&stk[cur][c - 64u];
      float4 so = (s == 31u) ? *(const float4*)&membL[n * 64u + d]
                             : *(const float4*)&stk[cur][c + 64u];
      float4 nv;
      nv.x = p0 * sp.x + p1 * so.x + p2 * scur.x;
      nv.y = p0 * sp.y + p1 * so.y + p2 * scur.y;
      nv.z = p0 * sp.z + p1 * so.z + p2 * scur.z;
      nv.w = p0 * sp.w + p1 * so.w + p2 * scur.w;
      *(float4*)&stk[nxt][c] = nv;
      if (last) *(float4*)&out[OUT_SR + b * 4096u + c] = nv;
    }
    __syncthreads();
  }
}

extern "C" void kernel_launch(void* const* d_in, const int* in_sizes, int n_in,
                              void* d_out, int out_size, void* d_ws, size_t ws_size,
                              hipStream_t stream) {
  const float* embs = (const float*)d_in[0];
  const int*   lens = (const int*)d_in[1];
  const float* We   = (const float*)d_in[2];
  const float* be   = (const float*)d_in[3];
  const float* Wh   = (const float*)d_in[4];
  const float* bh   = (const float*)d_in[5];
  const float* Wa   = (const float*)d_in[6];
  const float* ba   = (const float*)d_in[7];
  const float* Ws   = (const float*)d_in[8];
  const float* bs   = (const float*)d_in[9];
  const float* Wr   = (const float*)d_in[10];
  const float* br   = (const float*)d_in[11];
  const float* memb = (const float*)d_in[12];
  float* out = (float*)d_out;
  char* ws = (char*)d_ws;

  pack_kernel<<<1024, 256, 0, stream>>>(Wh, Wr, Ws, We, be, bh, br, ws);
  embed_kernel<<<2048, 256, 0, stream>>>(embs, ws, out);
  rnn_kernel<<<64, 1024, 0, stream>>>(lens, Wa, ba, bs, memb, ws, out);
}

// Round 2
// 3919.832 us; speedup vs baseline: 1.6062x; 1.6062x over previous
//
#include <hip/hip_runtime.h>
#include <hip/hip_bf16.h>
#include <hip/hip_fp16.h>
#include <stdint.h>

// Problem constants
constexpr int kT = 512;

// d_ws byte offsets. Wh/Wrs/Ws packed fp16, K-major [kb][row][8]; We stays bf16.
constexpr uint32_t WHP_OFF  = 0u;        // [64][512][8] fp16 : Wh[h][kb*8+e]
constexpr uint32_t WRSP_OFF = 524288u;   // [32][512][8] fp16 : Wr[h][jb*8+e]+Wr[512+h][jb*8+e]
constexpr uint32_t WSP_OFF  = 786432u;   // [64][128][8] fp16 : Ws[o][kb*8+e]
constexpr uint32_t WEP_OFF  = 917504u;   // [32][512][8] bf16 : We[h][kb*8+e]
constexpr uint32_t BIAS_OFF = 1179648u;  // [512] f32 : be+bh+br[h]+br[512+h]

// d_out element offsets (fp32)
constexpr uint32_t OUT_HL = 16777216u;
constexpr uint32_t OUT_SR = 16809984u;

static __device__ __forceinline__ float bitsf(uint32_t u) {
  union { uint32_t u; float f; } c; c.u = u; return c.f;
}

typedef _Float16 h2_t __attribute__((ext_vector_type(2)));

static __device__ __forceinline__ float dot2acc(uint32_t w, uint32_t h, float acc) {
#if __has_builtin(__builtin_amdgcn_fdot2)
  return __builtin_amdgcn_fdot2(__builtin_bit_cast(h2_t, w),
                                __builtin_bit_cast(h2_t, h), acc, false);
#else
  h2_t wv = __builtin_bit_cast(h2_t, w), hv = __builtin_bit_cast(h2_t, h);
  return acc + (float)wv.x * (float)hv.x + (float)wv.y * (float)hv.y;
#endif
}

// 8-term fp16xfp16 dot with fp32 accumulate: 4 v_dot2_f32_f16
static __device__ __forceinline__ float dot8h(uint4 w, uint4 h, float acc) {
  acc = dot2acc(w.x, h.x, acc);
  acc = dot2acc(w.y, h.y, acc);
  acc = dot2acc(w.z, h.z, acc);
  acc = dot2acc(w.w, h.w, acc);
  return acc;
}

// ---------------- kernel 0: pack weights (fp16/bf16) + fold biases ----------------
__global__ __launch_bounds__(256) void pack_kernel(
    const float* __restrict__ Wh, const float* __restrict__ Wr,
    const float* __restrict__ Ws, const float* __restrict__ We,
    const float* __restrict__ be, const float* __restrict__ bh,
    const float* __restrict__ br, char* __restrict__ ws)
{
  uint32_t g = blockIdx.x * 256u + threadIdx.x;
  __half* whp  = (__half*)(ws + WHP_OFF);
  __half* wrsp = (__half*)(ws + WRSP_OFF);
  __half* wsp  = (__half*)(ws + WSP_OFF);
  __hip_bfloat16* wep = (__hip_bfloat16*)(ws + WEP_OFF);
  float* bias = (float*)(ws + BIAS_OFF);

  if (g < 262144u) {  // WhP: idx = (kb*512+h)*8+e
    uint32_t e = g & 7u, h = (g >> 3) & 511u, kb = g >> 12;
    whp[g] = __float2half(Wh[h * 512u + kb * 8u + e]);
  }
  if (g < 131072u) {  // WrsP: sum the two stack blocks of Wr
    uint32_t e = g & 7u, h = (g >> 3) & 511u, jb = g >> 12;
    wrsp[g] = __float2half(Wr[h * 256u + jb * 8u + e] +
                           Wr[(512u + h) * 256u + jb * 8u + e]);
  }
  if (g < 65536u) {   // WsP: idx = (kb*128+o)*8+e
    uint32_t e = g & 7u, o = (g >> 3) & 127u, kb = g >> 10;
    wsp[g] = __float2half(Ws[o * 512u + kb * 8u + e]);
  }
  if (g < 131072u) {  // WeP: idx = (kb*512+h)*8+e, kb<32
    uint32_t e = g & 7u, h = (g >> 3) & 511u, kb = g >> 12;
    wep[g] = __float2bfloat16(We[h * 256u + kb * 8u + e]);
  }
  if (g < 512u) bias[g] = be[g] + bh[g] + br[g] + br[512u + g];
}

// ---------------- kernel 1: E[t,b,:] = emb @ We.T + all biases -> d_out output region --------
__global__ __launch_bounds__(256) void embed_kernel(
    const float* __restrict__ embs, const char* __restrict__ ws,
    float* __restrict__ out)
{
  __shared__ __align__(16) float embL[16 * 256];
  const uint32_t tid = threadIdx.x;
  const uint32_t r0 = blockIdx.x * 16u;
  #pragma unroll
  for (int i = 0; i < 16; i++) embL[tid + i * 256] = embs[r0 * 256u + tid + i * 256u];
  __syncthreads();

  const uint4* wep = (const uint4*)(ws + WEP_OFF);
  const float* bias = (const float*)(ws + BIAS_OFF);

  for (int hb = 0; hb < 2; hb++) {
    uint32_t h = hb * 256u + tid;
    float acc[16];
    #pragma unroll
    for (int r = 0; r < 16; r++) acc[r] = 0.f;
    for (int kb = 0; kb < 32; kb++) {
      uint4 v = wep[kb * 512u + h];
      float w0 = bitsf(v.x << 16), w1 = bitsf(v.x & 0xffff0000u);
      float w2 = bitsf(v.y << 16), w3 = bitsf(v.y & 0xffff0000u);
      float w4 = bitsf(v.z << 16), w5 = bitsf(v.z & 0xffff0000u);
      float w6 = bitsf(v.w << 16), w7 = bitsf(v.w & 0xffff0000u);
      #pragma unroll
      for (int r = 0; r < 16; r++) {
        const float4* e4 = (const float4*)&embL[r * 256 + kb * 8];
        float4 a = e4[0], c = e4[1];
        acc[r] += w0 * a.x + w1 * a.y + w2 * a.z + w3 * a.w
                + w4 * c.x + w5 * c.y + w6 * c.z + w7 * c.w;
      }
    }
    float bi = bias[h];
    #pragma unroll
    for (int r = 0; r < 16; r++) out[(r0 + r) * 512u + h] = acc[r] + bi;
  }
}

// ---------------- kernel 2: recurrence, one WG per batch, 2 barriers/step ----------
__global__ __launch_bounds__(1024) void rnn_kernel(
    const int* __restrict__ lens, const float* __restrict__ Wa,
    const float* __restrict__ ba, const float* __restrict__ bs,
    const float* __restrict__ memb, const char* __restrict__ ws,
    float* __restrict__ out)
{
  __shared__ __align__(16) float stk[2][4096];     // double-buffered stack [n][s][d]
  __shared__ __align__(16) float mhPart[1024];     // mhid partials
  __shared__ __align__(16) float psPart[8][128];   // push_pre partials
  __shared__ __align__(16) __half hidH[512];       // hidden state (fp16, single buffer)
  __shared__ __align__(16) __half topsH[256];      // stack[:, :2, :] snapshot (fp16)
  __shared__ __align__(16) __half waH[3072];       // Wa in LDS
  __shared__ __align__(16) float membL[128];
  __shared__ float lgts[8];
  __shared__ float bsL[128];
  __shared__ float baL[8];

  const uint32_t tid = threadIdx.x;
  const uint32_t b = blockIdx.x;
  const int len = lens[b];

  const uint4* whp  = (const uint4*)(ws + WHP_OFF);
  const uint4* wrsp = (const uint4*)(ws + WRSP_OFF);
  const uint4* wsp  = (const uint4*)(ws + WSP_OFF);
  const uint4* hH = (const uint4*)hidH;   // 64 fragments of 8 halfs
  const uint4* tH = (const uint4*)topsH;  // 32 fragments

  // ---- init state
  if (tid < 128) { membL[tid] = memb[tid]; bsL[tid] = bs[tid]; }
  if (tid < 512) hidH[tid] = __float2half(0.f);
  if (tid < 256) {  // tops = mem_bias for both depth cells
    uint32_t n = tid >> 7, d = tid & 63u;
    topsH[tid] = __float2half(memb[n * 64u + d]);
  }
  for (uint32_t i = tid; i < 3072u; i += 1024u) waH[i] = __float2half(Wa[i]);
  if (tid < 8) baL[tid] = (tid < 6) ? ba[tid] : 0.f;
  __syncthreads();
  {
    uint32_t c = tid * 4u, n = c >> 11, d = c & 63u;
    *(float4*)&stk[0][c] = *(const float4*)&membL[n * 64u + d];
  }
  __syncthreads();

  for (int t = 0; t < kT; t++) {
    const int cur = t & 1, nxt = cur ^ 1;

    // ---- P1: all matvec partials (read-only on state)
    {  // push_pre partials: 8 K-slices x 128 outputs
      uint32_t sub = tid >> 7, o = tid & 127u;
      float acc = 0.f;
      #pragma unroll
      for (int i = 0; i < 8; i++) {
        uint32_t kb = sub + (uint32_t)i * 8u;
        acc = dot8h(wsp[kb * 128u + o], hH[kb], acc);
      }
      psPart[sub][o] = acc;
    }
    if (tid < 384) {  // action logits: 6 waves, one per logit
      uint32_t o = tid >> 6, l = tid & 63u;
      float acc = 0.f;
      #pragma unroll
      for (int i = 0; i < 8; i++) {
        uint32_t idx = l + (uint32_t)i * 64u;
        acc += __half2float(waH[o * 512u + idx]) * __half2float(hidH[idx]);
      }
      #pragma unroll
      for (int off = 32; off; off >>= 1) acc += __shfl_down(acc, off, 64);
      if (l == 0) lgts[o] = acc + baL[o];
    }
    {  // mhid partials: 512 outputs x 2 K-halves; E already holds all biases
      uint32_t h = tid & 511u, half = tid >> 9;
      float acc = half ? 0.f : out[((uint32_t)t * 64u + b) * 512u + h];
      uint32_t kb0 = half * 32u;
      #pragma unroll 8
      for (int i = 0; i < 32; i++) {
        uint32_t kb = kb0 + (uint32_t)i;
        acc = dot8h(whp[kb * 512u + h], hH[kb], acc);
      }
      uint32_t jb0 = half * 16u;
      #pragma unroll 8
      for (int i = 0; i < 16; i++) {
        uint32_t jb = jb0 + (uint32_t)i;
        acc = dot8h(wrsp[jb * 512u + h], tH[jb], acc);
      }
      mhPart[tid] = acc;
    }
    __syncthreads();

    // ---- P2: finalize hid + stack blend (softmax & push_vals computed inline)
    const bool last = (t == len - 1);
    if (tid < 512) {
      float v = tanhf(mhPart[tid] + mhPart[tid + 512]);
      hidH[tid] = __float2half(v);
      out[((uint32_t)t * 64u + b) * 512u + tid] = v;
      if (last) out[OUT_HL + b * 512u + tid] = v;
    }
    {
      uint32_t c = tid * 4u;
      uint32_t n = c >> 11, s = (tid >> 4) & 31u, d = c & 63u;
      // inline softmax from logits (redundant per-thread, ~12 VALU)
      float l0 = lgts[n * 3u], l1 = lgts[n * 3u + 1u], l2 = lgts[n * 3u + 2u];
      float m = fmaxf(l0, fmaxf(l1, l2));
      float e0 = __expf(l0 - m), e1 = __expf(l1 - m), e2 = __expf(l2 - m);
      float inv = 1.f / (e0 + e1 + e2);
      float p0 = e0 * inv, p1 = e1 * inv, p2 = e2 * inv;

      float4 scur = *(const float4*)&stk[cur][c];
      float4 sp;
      if (s == 0) {  // top row: push_vals computed inline from partials
        float vv[4];
        #pragma unroll
        for (int j = 0; j < 4; j++) {
          uint32_t o = n * 64u + d + (uint32_t)j;
          float ss = bsL[o];
          #pragma unroll
          for (int k = 0; k < 8; k++) ss += psPart[k][o];
          vv[j] = tanhf(ss);
        }
        sp.x = vv[0]; sp.y = vv[1]; sp.z = vv[2]; sp.w = vv[3];
      } else {
        sp = *(const float4*)&stk[cur][c - 64u];
      }
      float4 so = (s == 31u) ? *(const float4*)&membL[n * 64u + d]
                             : *(const float4*)&stk[cur][c + 64u];
      float4 nv;
      nv.x = p0 * sp.x + p1 * so.x + p2 * scur.x;
      nv.y = p0 * sp.y + p1 * so.y + p2 * scur.y;
      nv.z = p0 * sp.z + p1 * so.z + p2 * scur.z;
      nv.w = p0 * sp.w + p1 * so.w + p2 * scur.w;
      *(float4*)&stk[nxt][c] = nv;
      if (s < 2u) {  // snapshot new tops (fp16) for next step's Wrs matvec
        uint32_t o = n * 128u + s * 64u + d;
        topsH[o + 0u] = __float2half(nv.x);
        topsH[o + 1u] = __float2half(nv.y);
        topsH[o + 2u] = __float2half(nv.z);
        topsH[o + 3u] = __float2half(nv.w);
      }
      if (last) *(float4*)&out[OUT_SR + b * 4096u + c] = nv;
    }
    __syncthreads();
  }
}

extern "C" void kernel_launch(void* const* d_in, const int* in_sizes, int n_in,
                              void* d_out, int out_size, void* d_ws, size_t ws_size,
                              hipStream_t stream) {
  const float* embs = (const float*)d_in[0];
  const int*   lens = (const int*)d_in[1];
  const float* We   = (const float*)d_in[2];
  const float* be   = (const float*)d_in[3];
  const float* Wh   = (const float*)d_in[4];
  const float* bh   = (const float*)d_in[5];
  const float* Wa   = (const float*)d_in[6];
  const float* ba   = (const float*)d_in[7];
  const float* Ws   = (const float*)d_in[8];
  const float* bs   = (const float*)d_in[9];
  const float* Wr   = (const float*)d_in[10];
  const float* br   = (const float*)d_in[11];
  const float* memb = (const float*)d_in[12];
  float* out = (float*)d_out;
  char* ws = (char*)d_ws;

  pack_kernel<<<1024, 256, 0, stream>>>(Wh, Wr, Ws, We, be, bh, br, ws);
  embed_kernel<<<2048, 256, 0, stream>>>(embs, ws, out);
  rnn_kernel<<<64, 1024, 0, stream>>>(lens, Wa, ba, bs, memb, ws, out);
}

// Round 3
// 3706.120 us; speedup vs baseline: 1.6988x; 1.0577x over previous
//
#include <hip/hip_runtime.h>
#include <hip/hip_bf16.h>
#include <hip/hip_fp16.h>
#include <stdint.h>

constexpr int kT = 512;

// d_ws byte offsets
constexpr uint32_t WHP_OFF  = 0u;        // [64][512][8] fp16 : Wh[h][kb*8+e]
constexpr uint32_t WRSP_OFF = 524288u;   // [32][512][8] fp16 : Wr+Wr' summed
constexpr uint32_t WSP_OFF  = 786432u;   // [64][128][8] fp16 : Ws[o][kb*8+e]
constexpr uint32_t WEP_OFF  = 917504u;   // [32][512][8] bf16 : We[h][kb*8+e]
constexpr uint32_t BIAS_OFF = 1179648u;  // [512] f32
constexpr uint32_t FLAG_OFF = 1181696u;  // [512][64] u32 arrival counters (128 KB)
constexpr uint32_t X_OFF    = 1312768u;  // [2][64][4][160] f32 exchange (320 KB)

// d_out element offsets (fp32)
constexpr uint32_t OUT_HL = 16777216u;
constexpr uint32_t OUT_SR = 16809984u;

static __device__ __forceinline__ float bitsf(uint32_t u) {
  union { uint32_t u; float f; } c; c.u = u; return c.f;
}

typedef _Float16 h2_t __attribute__((ext_vector_type(2)));

static __device__ __forceinline__ float dot2acc(uint32_t w, uint32_t h, float acc) {
#if __has_builtin(__builtin_amdgcn_fdot2)
  return __builtin_amdgcn_fdot2(__builtin_bit_cast(h2_t, w),
                                __builtin_bit_cast(h2_t, h), acc, false);
#else
  h2_t wv = __builtin_bit_cast(h2_t, w), hv = __builtin_bit_cast(h2_t, h);
  return acc + (float)wv.x * (float)hv.x + (float)wv.y * (float)hv.y;
#endif
}

static __device__ __forceinline__ float dot8h(uint4 w, uint4 h, float acc) {
  acc = dot2acc(w.x, h.x, acc);
  acc = dot2acc(w.y, h.y, acc);
  acc = dot2acc(w.z, h.z, acc);
  acc = dot2acc(w.w, h.w, acc);
  return acc;
}

// ---------------- kernel 0: pack weights + fold biases + zero flags ----------------
__global__ __launch_bounds__(256) void pack_kernel(
    const float* __restrict__ Wh, const float* __restrict__ Wr,
    const float* __restrict__ Ws, const float* __restrict__ We,
    const float* __restrict__ be, const float* __restrict__ bh,
    const float* __restrict__ br, char* __restrict__ ws)
{
  uint32_t g = blockIdx.x * 256u + threadIdx.x;
  __half* whp  = (__half*)(ws + WHP_OFF);
  __half* wrsp = (__half*)(ws + WRSP_OFF);
  __half* wsp  = (__half*)(ws + WSP_OFF);
  __hip_bfloat16* wep = (__hip_bfloat16*)(ws + WEP_OFF);
  float* bias = (float*)(ws + BIAS_OFF);
  uint32_t* flags = (uint32_t*)(ws + FLAG_OFF);

  if (g < 262144u) {
    uint32_t e = g & 7u, h = (g >> 3) & 511u, kb = g >> 12;
    whp[g] = __float2half(Wh[h * 512u + kb * 8u + e]);
  }
  if (g < 131072u) {
    uint32_t e = g & 7u, h = (g >> 3) & 511u, jb = g >> 12;
    wrsp[g] = __float2half(Wr[h * 256u + jb * 8u + e] +
                           Wr[(512u + h) * 256u + jb * 8u + e]);
  }
  if (g < 65536u) {
    uint32_t e = g & 7u, o = (g >> 3) & 127u, kb = g >> 10;
    wsp[g] = __float2half(Ws[o * 512u + kb * 8u + e]);
  }
  if (g < 131072u) {
    uint32_t e = g & 7u, h = (g >> 3) & 511u, kb = g >> 12;
    wep[g] = __float2bfloat16(We[h * 256u + kb * 8u + e]);
  }
  if (g < 512u) bias[g] = be[g] + bh[g] + br[g] + br[512u + g];
  if (g < 32768u) flags[g] = 0u;
}

// ---------------- kernel 1: E = emb @ We.T + biases -> d_out output region --------
__global__ __launch_bounds__(256) void embed_kernel(
    const float* __restrict__ embs, const char* __restrict__ ws,
    float* __restrict__ out)
{
  __shared__ __align__(16) float embL[16 * 256];
  const uint32_t tid = threadIdx.x;
  const uint32_t r0 = blockIdx.x * 16u;
  #pragma unroll
  for (int i = 0; i < 16; i++) embL[tid + i * 256] = embs[r0 * 256u + tid + i * 256u];
  __syncthreads();

  const uint4* wep = (const uint4*)(ws + WEP_OFF);
  const float* bias = (const float*)(ws + BIAS_OFF);

  for (int hb = 0; hb < 2; hb++) {
    uint32_t h = hb * 256u + tid;
    float acc[16];
    #pragma unroll
    for (int r = 0; r < 16; r++) acc[r] = 0.f;
    for (int kb = 0; kb < 32; kb++) {
      uint4 v = wep[kb * 512u + h];
      float w0 = bitsf(v.x << 16), w1 = bitsf(v.x & 0xffff0000u);
      float w2 = bitsf(v.y << 16), w3 = bitsf(v.y & 0xffff0000u);
      float w4 = bitsf(v.z << 16), w5 = bitsf(v.z & 0xffff0000u);
      float w6 = bitsf(v.w << 16), w7 = bitsf(v.w & 0xffff0000u);
      #pragma unroll
      for (int r = 0; r < 16; r++) {
        const float4* e4 = (const float4*)&embL[r * 256 + kb * 8];
        float4 a = e4[0], c = e4[1];
        acc[r] += w0 * a.x + w1 * a.y + w2 * a.z + w3 * a.w
                + w4 * c.x + w5 * c.y + w6 * c.z + w7 * c.w;
      }
    }
    float bi = bias[h];
    #pragma unroll
    for (int r = 0; r < 16; r++) out[(r0 + r) * 512u + h] = acc[r] + bi;
  }
}

// ---------------- kernel 2: recurrence, 4 WGs per batch, device-scope exchange ----------
__global__ __launch_bounds__(1024) void rnn_kernel(
    const int* __restrict__ lens, const float* __restrict__ Wa,
    const float* __restrict__ ba, const float* __restrict__ bs,
    const float* __restrict__ memb, char* __restrict__ ws,
    float* __restrict__ out)
{
  __shared__ __align__(16) uint4 wrsL[32 * 128];   // 64 KB: Wrs quarter [jb][r]
  __shared__ __align__(16) uint4 wsL[32 * 64];     // 32 KB: Ws quarter [row][kb]
  __shared__ __align__(16) float stk[2][4096];     // 32 KB: stack dbuf (replicated)
  __shared__ __align__(16) __half waH[3072];       //  6 KB: Wa fp16
  __shared__ __align__(16) __half hH[512];         //  1 KB, perm layout
  __shared__ __align__(16) __half tH[256];         //  perm layout
  __shared__ __align__(16) float pvL[128];
  __shared__ __align__(16) float membL[128];
  __shared__ float bsL[128];
  __shared__ float lgts[8];
  __shared__ float baL[8];
  __shared__ int sAbort;

  const uint32_t tid = threadIdx.x;
  const uint32_t wg = blockIdx.x;
  const uint32_t q = wg >> 6;      // quarter 0..3   (wg = q*64 + b keeps a batch's
  const uint32_t b = wg & 63u;     // batch          4 WGs on one XCD: 64 % 8 == 0)
  const int len = lens[b];
  const uint32_t r = tid >> 3, s = tid & 7u;
  const uint32_t h = q * 128u + r;

  const uint4* whp  = (const uint4*)(ws + WHP_OFF);
  const uint4* wrsp = (const uint4*)(ws + WRSP_OFF);
  const uint4* wsp  = (const uint4*)(ws + WSP_OFF);
  uint32_t* flags = (uint32_t*)(ws + FLAG_OFF);
  float* X = (float*)(ws + X_OFF);

  const uint4* hHf = (const uint4*)hH;
  const uint4* tHf = (const uint4*)tH;

  // ---- Wh quarter -> VGPRs (32 regs)
  uint4 wh[8];
  #pragma unroll
  for (int i = 0; i < 8; i++) wh[i] = whp[(s * 8u + (uint32_t)i) * 512u + h];

  // ---- stage Wrs quarter (4096 fragments) and Ws quarter (2048 fragments) into LDS
  #pragma unroll
  for (int i = 0; i < 4; i++) {
    uint32_t f = tid * 4u + (uint32_t)i;           // f = jb*128 + rr
    uint32_t jb = f >> 7, rr = f & 127u;
    wrsL[f] = wrsp[jb * 512u + q * 128u + rr];
  }
  #pragma unroll
  for (int i = 0; i < 2; i++) {
    uint32_t f = tid * 2u + (uint32_t)i;           // f = row*64 + kb
    uint32_t row = f >> 6, kb = f & 63u;
    wsL[f] = wsp[kb * 128u + q * 32u + row];
  }
  for (uint32_t i = tid; i < 3072u; i += 1024u) waH[i] = __float2half(Wa[i]);
  if (tid < 128u) { membL[tid] = memb[tid]; bsL[tid] = bs[tid]; }
  if (tid < 64u)  ((uint4*)hH)[tid] = uint4{0u, 0u, 0u, 0u};
  if (tid < 256u) {  // tops init = mem_bias, perm layout
    uint32_t jb = tid >> 3, e = tid & 7u;
    uint32_t n = tid >> 7, d = tid & 63u;
    uint32_t ph = ((jb & 3u) << 3) | (jb >> 2);
    ((__half*)tH)[ph * 8u + e] = __float2half(memb[n * 64u + d]);
  }
  if (tid < 8u) baL[tid] = (tid < 6u) ? ba[tid] : 0.f;
  if (tid == 0) sAbort = 0;
  __syncthreads();
  {
    uint32_t c = tid * 4u, n = c >> 11, d = c & 63u;
    *(float4*)&stk[0][c] = *(const float4*)&membL[n * 64u + d];
  }
  float eCur = 0.f;
  if (s == 0) eCur = out[b * 512u + h];
  __syncthreads();

  for (int t = 0; t < kT; t++) {
    const int cur = t & 1, nxt = cur ^ 1;
    const uint32_t p = (uint32_t)cur;
    const bool lastT = (t == len - 1);

    // prefetch next step's E (consumed next iteration -> full latency hidden)
    float eNext = 0.f;
    if (s == 0 && t < kT - 1) eNext = out[((uint32_t)(t + 1) * 64u + b) * 512u + h];

    // ---- A1: mhid row h (Wh from VGPRs, Wrs from LDS, hid/tops from perm-LDS)
    float acc = 0.f;
    #pragma unroll
    for (int i = 0; i < 8; i++)
      acc = dot8h(wh[i], hHf[(uint32_t)i * 8u + s], acc);   // kb = s*8+i
    #pragma unroll
    for (int i = 0; i < 4; i++) {
      uint32_t jb = s * 4u + (uint32_t)i;
      acc = dot8h(wrsL[jb * 128u + r], tHf[(uint32_t)i * 8u + s], acc);
    }
    acc += __shfl_xor(acc, 1, 64);
    acc += __shfl_xor(acc, 2, 64);
    acc += __shfl_xor(acc, 4, 64);
    if (s == 0) {
      float v = tanhf(acc + eCur);
      out[((uint32_t)t * 64u + b) * 512u + h] = v;
      if (lastT) out[OUT_HL + b * 512u + h] = v;
      __hip_atomic_store(&X[((p * 64u + b) * 4u + q) * 160u + r], v,
                         __ATOMIC_RELAXED, __HIP_MEMORY_SCOPE_AGENT);
    }
    eCur = eNext;

    // ---- A2: push_vals quarter (32 rows, 32 threads each)
    {
      uint32_t wrow = tid >> 5, kt = tid & 31u;
      float wa2 = 0.f;
      #pragma unroll
      for (int j = 0; j < 2; j++) {
        uint32_t kb = kt * 2u + (uint32_t)j;
        uint32_t ph = ((kb & 7u) << 3) | (kb >> 3);
        wa2 = dot8h(wsL[wrow * 64u + kb], hHf[ph], wa2);
      }
      #pragma unroll
      for (int off = 1; off <= 16; off <<= 1) wa2 += __shfl_xor(wa2, off, 64);
      if (kt == 0) {
        float pvv = tanhf(wa2 + bsL[q * 32u + wrow]);
        __hip_atomic_store(&X[((p * 64u + b) * 4u + q) * 160u + 128u + wrow], pvv,
                           __ATOMIC_RELAXED, __HIP_MEMORY_SCOPE_AGENT);
      }
    }
    // ---- A3: action logits (computed identically in all 4 WGs)
    if (tid < 384u) {
      uint32_t o = tid >> 6, kb = tid & 63u;
      uint32_t ph = ((kb & 7u) << 3) | (kb >> 3);
      float la = dot8h(((const uint4*)waH)[o * 64u + kb], hHf[ph], 0.f);
      #pragma unroll
      for (int off = 1; off <= 32; off <<= 1) la += __shfl_xor(la, off, 64);
      if (kb == 0) lgts[o] = la + baL[o];
    }
    __syncthreads();  // drains all X stores (vmcnt 0) before the flag

    // ---- group rendezvous
    if (tid == 0) {
      uint32_t* fl = &flags[(uint32_t)t * 64u + b];
      __hip_atomic_fetch_add(fl, 1u, __ATOMIC_RELEASE, __HIP_MEMORY_SCOPE_AGENT);
      uint32_t guard = 0;
      while (__hip_atomic_load(fl, __ATOMIC_ACQUIRE, __HIP_MEMORY_SCOPE_AGENT) < 4u) {
        if (++guard > (1u << 22)) { sAbort = 1; break; }
      }
    }
    __syncthreads();
    if (sAbort) return;

    // ---- B: gather full hid (fp16, perm layout) + push_vals
    if (tid < 512u) {
      uint32_t j = tid >> 7, k = tid & 127u;
      float hv = __hip_atomic_load(&X[((p * 64u + b) * 4u + j) * 160u + k],
                                   __ATOMIC_RELAXED, __HIP_MEMORY_SCOPE_AGENT);
      uint32_t kb = tid >> 3, e = tid & 7u;
      uint32_t ph = ((kb & 7u) << 3) | (kb >> 3);
      ((__half*)hH)[ph * 8u + e] = __float2half(hv);
    } else if (tid < 640u) {
      uint32_t f = tid - 512u, j = f >> 5;
      pvL[f] = __hip_atomic_load(&X[((p * 64u + b) * 4u + j) * 160u + 128u + (f & 31u)],
                                 __ATOMIC_RELAXED, __HIP_MEMORY_SCOPE_AGENT);
    }
    __syncthreads();

    // ---- C: stack blend (replicated, bit-identical across the 4 WGs)
    {
      uint32_t c = tid * 4u;
      uint32_t n = c >> 11, sd = (tid >> 4) & 31u, d = c & 63u;
      float l0 = lgts[n * 3u], l1 = lgts[n * 3u + 1u], l2 = lgts[n * 3u + 2u];
      float m = fmaxf(l0, fmaxf(l1, l2));
      float e0 = __expf(l0 - m), e1 = __expf(l1 - m), e2 = __expf(l2 - m);
      float inv = 1.f / (e0 + e1 + e2);
      float p0 = e0 * inv, p1 = e1 * inv, p2 = e2 * inv;
      float4 scur = *(const float4*)&stk[cur][c];
      float4 sp = (sd == 0) ? *(const float4*)&pvL[n * 64u + d]
                            : *(const float4*)&stk[cur][c - 64u];
      float4 so = (sd == 31u) ? *(const float4*)&membL[n * 64u + d]
                              : *(const float4*)&stk[cur][c + 64u];
      float4 nv;
      nv.x = p0 * sp.x + p1 * so.x + p2 * scur.x;
      nv.y = p0 * sp.y + p1 * so.y + p2 * scur.y;
      nv.z = p0 * sp.z + p1 * so.z + p2 * scur.z;
      nv.w = p0 * sp.w + p1 * so.w + p2 * scur.w;
      *(float4*)&stk[nxt][c] = nv;
      if (sd < 2u) {  // new tops -> perm-layout fp16 (4 consecutive halfs, 8B store)
        uint32_t f = n * 128u + sd * 64u + d;
        uint32_t jb = f >> 3, e = f & 7u;
        uint32_t ph = ((jb & 3u) << 3) | (jb >> 2);
        uint32_t lo = ((uint32_t)__half_as_ushort(__float2half(nv.y)) << 16) |
                      __half_as_ushort(__float2half(nv.x));
        uint32_t hi = ((uint32_t)__half_as_ushort(__float2half(nv.w)) << 16) |
                      __half_as_ushort(__float2half(nv.z));
        *(uint2*)((__half*)tH + ph * 8u + e) = uint2{lo, hi};
      }
      if (lastT && q == 0u) *(float4*)&out[OUT_SR + b * 4096u + c] = nv;
    }
    __syncthreads();
  }
}

extern "C" void kernel_launch(void* const* d_in, const int* in_sizes, int n_in,
                              void* d_out, int out_size, void* d_ws, size_t ws_size,
                              hipStream_t stream) {
  const float* embs = (const float*)d_in[0];
  const int*   lens = (const int*)d_in[1];
  const float* We   = (const float*)d_in[2];
  const float* be   = (const float*)d_in[3];
  const float* Wh   = (const float*)d_in[4];
  const float* bh   = (const float*)d_in[5];
  const float* Wa   = (const float*)d_in[6];
  const float* ba   = (const float*)d_in[7];
  const float* Ws   = (const float*)d_in[8];
  const float* bs   = (const float*)d_in[9];
  const float* Wr   = (const float*)d_in[10];
  const float* br   = (const float*)d_in[11];
  const float* memb = (const float*)d_in[12];
  float* out = (float*)d_out;
  char* ws = (char*)d_ws;

  pack_kernel<<<1024, 256, 0, stream>>>(Wh, Wr, Ws, We, be, bh, br, ws);
  embed_kernel<<<2048, 256, 0, stream>>>(embs, ws, out);
  rnn_kernel<<<256, 1024, 0, stream>>>(lens, Wa, ba, bs, memb, ws, out);
}

// Round 4
// 1280.940 us; speedup vs baseline: 4.9152x; 2.8933x over previous
//
#include <hip/hip_runtime.h>
#include <hip/hip_bf16.h>
#include <hip/hip_fp16.h>
#include <stdint.h>

constexpr int kT = 512;

// d_ws byte offsets
constexpr uint32_t WHP_OFF  = 0u;        // [64][512][8] fp16 : Wh[h][kb*8+e]
constexpr uint32_t WRSP_OFF = 524288u;   // [32][512][8] fp16 : Wr+Wr' summed
constexpr uint32_t WSP_OFF  = 786432u;   // [64][128][8] fp16 : Ws[o][kb*8+e]
constexpr uint32_t WEP_OFF  = 917504u;   // [32][512][8] bf16 : We[h][kb*8+e]
constexpr uint32_t BIAS_OFF = 1179648u;  // [512] f32
constexpr uint32_t X_OFF    = 1181696u;  // [2][64][4][128] u32 tag|fp16 exchange (256 KB)

// d_out element offsets (fp32)
constexpr uint32_t OUT_HL = 16777216u;
constexpr uint32_t OUT_SR = 16809984u;

static __device__ __forceinline__ float bitsf(uint32_t u) {
  union { uint32_t u; float f; } c; c.u = u; return c.f;
}

typedef _Float16 h2_t __attribute__((ext_vector_type(2)));

static __device__ __forceinline__ float dot2acc(uint32_t w, uint32_t h, float acc) {
#if __has_builtin(__builtin_amdgcn_fdot2)
  return __builtin_amdgcn_fdot2(__builtin_bit_cast(h2_t, w),
                                __builtin_bit_cast(h2_t, h), acc, false);
#else
  h2_t wv = __builtin_bit_cast(h2_t, w), hv = __builtin_bit_cast(h2_t, h);
  return acc + (float)wv.x * (float)hv.x + (float)wv.y * (float)hv.y;
#endif
}

static __device__ __forceinline__ float dot8h(uint4 w, uint4 h, float acc) {
  acc = dot2acc(w.x, h.x, acc);
  acc = dot2acc(w.y, h.y, acc);
  acc = dot2acc(w.z, h.z, acc);
  acc = dot2acc(w.w, h.w, acc);
  return acc;
}

// ---------------- kernel 0: pack weights + fold biases ----------------
__global__ __launch_bounds__(256) void pack_kernel(
    const float* __restrict__ Wh, const float* __restrict__ Wr,
    const float* __restrict__ Ws, const float* __restrict__ We,
    const float* __restrict__ be, const float* __restrict__ bh,
    const float* __restrict__ br, char* __restrict__ ws)
{
  uint32_t g = blockIdx.x * 256u + threadIdx.x;
  __half* whp  = (__half*)(ws + WHP_OFF);
  __half* wrsp = (__half*)(ws + WRSP_OFF);
  __half* wsp  = (__half*)(ws + WSP_OFF);
  __hip_bfloat16* wep = (__hip_bfloat16*)(ws + WEP_OFF);
  float* bias = (float*)(ws + BIAS_OFF);

  if (g < 262144u) {
    uint32_t e = g & 7u, h = (g >> 3) & 511u, kb = g >> 12;
    whp[g] = __float2half(Wh[h * 512u + kb * 8u + e]);
  }
  if (g < 131072u) {
    uint32_t e = g & 7u, h = (g >> 3) & 511u, jb = g >> 12;
    wrsp[g] = __float2half(Wr[h * 256u + jb * 8u + e] +
                           Wr[(512u + h) * 256u + jb * 8u + e]);
  }
  if (g < 65536u) {
    uint32_t e = g & 7u, o = (g >> 3) & 127u, kb = g >> 10;
    wsp[g] = __float2half(Ws[o * 512u + kb * 8u + e]);
  }
  if (g < 131072u) {
    uint32_t e = g & 7u, h = (g >> 3) & 511u, kb = g >> 12;
    wep[g] = __float2bfloat16(We[h * 256u + kb * 8u + e]);
  }
  if (g < 512u) bias[g] = be[g] + bh[g] + br[g] + br[512u + g];
}

// ---------------- kernel 1: E = emb @ We.T + biases -> d_out output region --------
__global__ __launch_bounds__(256) void embed_kernel(
    const float* __restrict__ embs, const char* __restrict__ ws,
    float* __restrict__ out)
{
  __shared__ __align__(16) float embL[16 * 256];
  const uint32_t tid = threadIdx.x;
  const uint32_t r0 = blockIdx.x * 16u;
  #pragma unroll
  for (int i = 0; i < 16; i++) embL[tid + i * 256] = embs[r0 * 256u + tid + i * 256u];
  __syncthreads();

  const uint4* wep = (const uint4*)(ws + WEP_OFF);
  const float* bias = (const float*)(ws + BIAS_OFF);

  for (int hb = 0; hb < 2; hb++) {
    uint32_t h = hb * 256u + tid;
    float acc[16];
    #pragma unroll
    for (int r = 0; r < 16; r++) acc[r] = 0.f;
    for (int kb = 0; kb < 32; kb++) {
      uint4 v = wep[kb * 512u + h];
      float w0 = bitsf(v.x << 16), w1 = bitsf(v.x & 0xffff0000u);
      float w2 = bitsf(v.y << 16), w3 = bitsf(v.y & 0xffff0000u);
      float w4 = bitsf(v.z << 16), w5 = bitsf(v.z & 0xffff0000u);
      float w6 = bitsf(v.w << 16), w7 = bitsf(v.w & 0xffff0000u);
      #pragma unroll
      for (int r = 0; r < 16; r++) {
        const float4* e4 = (const float4*)&embL[r * 256 + kb * 8];
        float4 a = e4[0], c = e4[1];
        acc[r] += w0 * a.x + w1 * a.y + w2 * a.z + w3 * a.w
                + w4 * c.x + w5 * c.y + w6 * c.z + w7 * c.w;
      }
    }
    float bi = bias[h];
    #pragma unroll
    for (int r = 0; r < 16; r++) out[(r0 + r) * 512u + h] = acc[r] + bi;
  }
}

// ---------------- kernel 2: recurrence, 4 WGs/batch, tag-in-data fp16 exchange ----------
__global__ __launch_bounds__(1024) void rnn_kernel(
    const int* __restrict__ lens, const float* __restrict__ Wa,
    const float* __restrict__ ba, const float* __restrict__ bs,
    const float* __restrict__ memb, char* __restrict__ ws,
    float* __restrict__ out)
{
  __shared__ __align__(16) float stk[2][4096];    // 32 KB stack dbuf (replicated)
  __shared__ __align__(16) __half waH[3072];      //  6 KB Wa fp16
  __shared__ __align__(16) __half hH[2][512];     //  2 KB hid dbuf, perm layout
  __shared__ __align__(16) __half tH[2][256];     //  1 KB tops dbuf, perm layout
  __shared__ __align__(16) float pvL[128];
  __shared__ __align__(16) float membL[128];
  __shared__ float bsL[128];
  __shared__ float lgts[8];
  __shared__ float baL[8];

  const uint32_t tid = threadIdx.x;
  const uint32_t wg = blockIdx.x;
  const uint32_t q = wg >> 6;      // quarter 0..3 (wg = q*64+b keeps group on one XCD)
  const uint32_t b = wg & 63u;
  const int len = lens[b];
  const uint32_t r = tid >> 3, s = tid & 7u;   // row-in-quarter, K-slice
  const uint32_t h = q * 128u + r;

  const uint4* whp  = (const uint4*)(ws + WHP_OFF);
  const uint4* wrsp = (const uint4*)(ws + WRSP_OFF);
  const uint4* wsp  = (const uint4*)(ws + WSP_OFF);
  uint32_t* X32 = (uint32_t*)(ws + X_OFF);

  // ---- all weights into VGPRs: Wh quarter 32 + Wrs quarter 16 + Ws FULL 32 = 80 regs
  uint4 wh[8], wrs[4], wsr[8];
  #pragma unroll
  for (int i = 0; i < 8; i++) wh[i]  = whp[(s * 8u + (uint32_t)i) * 512u + h];
  #pragma unroll
  for (int i = 0; i < 4; i++) wrs[i] = wrsp[(s * 4u + (uint32_t)i) * 512u + h];
  #pragma unroll
  for (int j = 0; j < 8; j++) wsr[j] = wsp[(s * 8u + (uint32_t)j) * 128u + r];

  for (uint32_t i = tid; i < 3072u; i += 1024u) waH[i] = __float2half(Wa[i]);
  if (tid < 128u) { membL[tid] = memb[tid]; bsL[tid] = bs[tid]; }
  if (tid < 64u)  ((uint4*)hH[0])[tid] = uint4{0u, 0u, 0u, 0u};
  if (tid < 256u) {  // tops init = mem_bias, perm layout
    uint32_t jb = tid >> 3, e = tid & 7u, n = tid >> 7, d = tid & 63u;
    uint32_t pt = ((jb & 3u) << 3) | (jb >> 2);
    ((__half*)tH[0])[pt * 8u + e] = __float2half(memb[n * 64u + d]);
  }
  if (tid < 8u) baL[tid] = (tid < 6u) ? ba[tid] : 0.f;
  __syncthreads();
  {
    uint32_t c = tid * 4u, n = c >> 11, d = c & 63u;
    *(float4*)&stk[0][c] = *(const float4*)&membL[n * 64u + d];
  }
  float eCur = (s == 0) ? out[b * 512u + h] : 0.f;
  __syncthreads();

  for (int t = 0; t < kT; t++) {
    const int cur = t & 1, nxt = cur ^ 1;
    const bool lastT = (t == len - 1);
    const uint4* hc = (const uint4*)hH[cur];
    const uint4* tc = (const uint4*)tH[cur];

    float eNext = (s == 0 && t < kT - 1)
                ? out[((uint32_t)(t + 1) * 64u + b) * 512u + h] : 0.f;

    // ---- A1: mhid row h (all weights in VGPRs; hid/tops broadcast from perm-LDS)
    float acc = 0.f;
    #pragma unroll
    for (int i = 0; i < 8; i++) acc = dot8h(wh[i], hc[(uint32_t)i * 8u + s], acc);
    #pragma unroll
    for (int i = 0; i < 4; i++) acc = dot8h(wrs[i], tc[(uint32_t)i * 8u + s], acc);
    acc += __shfl_xor(acc, 1, 64);
    acc += __shfl_xor(acc, 2, 64);
    acc += __shfl_xor(acc, 4, 64);
    if (s == 0) {
      float v = tanhf(acc + eCur);
      out[((uint32_t)t * 64u + b) * 512u + h] = v;
      if (lastT) out[OUT_HL + b * 512u + h] = v;
      __half vh = __float2half(v);
      uint32_t pay = ((uint32_t)(t + 1) << 16) | (uint32_t)__half_as_ushort(vh);
      __hip_atomic_store(&X32[(((uint32_t)cur * 64u + b) * 4u + q) * 128u + r], pay,
                         __ATOMIC_RELAXED, __HIP_MEMORY_SCOPE_AGENT);
      uint32_t kb = h >> 3, e = h & 7u;
      uint32_t ph = ((kb & 7u) << 3) | (kb >> 3);
      ((__half*)hH[nxt])[ph * 8u + e] = vh;   // own quarter, next buffer
    }
    eCur = eNext;

    // ---- A2: FULL push_vals (replicated; Ws in VGPRs -> no exchange needed)
    float wa2 = 0.f;
    #pragma unroll
    for (int j = 0; j < 8; j++) wa2 = dot8h(wsr[j], hc[((uint32_t)j << 3) | s], wa2);
    wa2 += __shfl_xor(wa2, 1, 64);
    wa2 += __shfl_xor(wa2, 2, 64);
    wa2 += __shfl_xor(wa2, 4, 64);
    if (s == 0) pvL[r] = tanhf(wa2 + bsL[r]);

    // ---- A3: action logits (replicated)
    if (tid < 384u) {
      uint32_t o = tid >> 6, kb = tid & 63u;
      uint32_t ph = ((kb & 7u) << 3) | (kb >> 3);
      float la = dot8h(((const uint4*)waH)[o * 64u + kb], hc[ph], 0.f);
      #pragma unroll
      for (int off = 1; off <= 32; off <<= 1) la += __shfl_xor(la, off, 64);
      if (kb == 0) lgts[o] = la + baL[o];
    }
    __syncthreads();

    // ---- C: stack blend (replicated, bit-identical across the 4 WGs)
    {
      uint32_t c = tid * 4u;
      uint32_t n = c >> 11, sd = (tid >> 4) & 31u, d = c & 63u;
      float l0 = lgts[n * 3u], l1 = lgts[n * 3u + 1u], l2 = lgts[n * 3u + 2u];
      float m = fmaxf(l0, fmaxf(l1, l2));
      float e0 = __expf(l0 - m), e1 = __expf(l1 - m), e2 = __expf(l2 - m);
      float inv = 1.f / (e0 + e1 + e2);
      float p0 = e0 * inv, p1 = e1 * inv, p2 = e2 * inv;
      float4 scur = *(const float4*)&stk[cur][c];
      float4 sp = (sd == 0) ? *(const float4*)&pvL[n * 64u + d]
                            : *(const float4*)&stk[cur][c - 64u];
      float4 so = (sd == 31u) ? *(const float4*)&membL[n * 64u + d]
                              : *(const float4*)&stk[cur][c + 64u];
      float4 nv;
      nv.x = p0 * sp.x + p1 * so.x + p2 * scur.x;
      nv.y = p0 * sp.y + p1 * so.y + p2 * scur.y;
      nv.z = p0 * sp.z + p1 * so.z + p2 * scur.z;
      nv.w = p0 * sp.w + p1 * so.w + p2 * scur.w;
      *(float4*)&stk[nxt][c] = nv;
      if (sd < 2u) {  // new tops -> perm-layout fp16 (next buffer)
        uint32_t f = n * 128u + sd * 64u + d;
        uint32_t jb = f >> 3, e = f & 7u;
        uint32_t pt = ((jb & 3u) << 3) | (jb >> 2);
        uint32_t lo = ((uint32_t)__half_as_ushort(__float2half(nv.y)) << 16) |
                      __half_as_ushort(__float2half(nv.x));
        uint32_t hi = ((uint32_t)__half_as_ushort(__float2half(nv.w)) << 16) |
                      __half_as_ushort(__float2half(nv.z));
        *(uint2*)((__half*)tH[nxt] + pt * 8u + e) = uint2{lo, hi};
      }
      if (lastT && q == 0u) *(float4*)&out[OUT_SR + b * 4096u + c] = nv;
    }

    // ---- gather the 3 foreign hid quarters (store latency hidden under A2/A3/C)
    if (t < kT - 1 && tid < 384u) {
      uint32_t j = tid >> 7;
      uint32_t jj = j + (j >= q ? 1u : 0u);
      uint32_t k = tid & 127u;
      uint32_t* src = &X32[(((uint32_t)cur * 64u + b) * 4u + jj) * 128u + k];
      const uint32_t want = (uint32_t)(t + 1) << 16;
      uint32_t x = __hip_atomic_load(src, __ATOMIC_RELAXED, __HIP_MEMORY_SCOPE_AGENT);
      uint32_t g = 0;
      while ((x & 0xffff0000u) != want) {
        x = __hip_atomic_load(src, __ATOMIC_RELAXED, __HIP_MEMORY_SCOPE_AGENT);
        if (++g > (1u << 24)) break;   // bounded: no hang even if model wrong
      }
      uint32_t idx = jj * 128u + k, kb = idx >> 3, e = idx & 7u;
      uint32_t ph = ((kb & 7u) << 3) | (kb >> 3);
      ((__half*)hH[nxt])[ph * 8u + e] = __ushort_as_half((unsigned short)(x & 0xffffu));
    }
    __syncthreads();
  }
}

extern "C" void kernel_launch(void* const* d_in, const int* in_sizes, int n_in,
                              void* d_out, int out_size, void* d_ws, size_t ws_size,
                              hipStream_t stream) {
  const float* embs = (const float*)d_in[0];
  const int*   lens = (const int*)d_in[1];
  const float* We   = (const float*)d_in[2];
  const float* be   = (const float*)d_in[3];
  const float* Wh   = (const float*)d_in[4];
  const float* bh   = (const float*)d_in[5];
  const float* Wa   = (const float*)d_in[6];
  const float* ba   = (const float*)d_in[7];
  const float* Ws   = (const float*)d_in[8];
  const float* bs   = (const float*)d_in[9];
  const float* Wr   = (const float*)d_in[10];
  const float* br   = (const float*)d_in[11];
  const float* memb = (const float*)d_in[12];
  float* out = (float*)d_out;
  char* ws = (char*)d_ws;

  pack_kernel<<<1024, 256, 0, stream>>>(Wh, Wr, Ws, We, be, bh, br, ws);
  embed_kernel<<<2048, 256, 0, stream>>>(embs, ws, out);
  rnn_kernel<<<256, 1024, 0, stream>>>(lens, Wa, ba, bs, memb, ws, out);
}